// Round 19
// baseline (446.212 us; speedup 1.0000x reference)
//
#include <hip/hip_runtime.h>
#include <cstdint>
#include <cstddef>

#define BT 4
#define CC 96
#define HH 64
#define WW 256
#define LL (HH*WW)    // 16384
#define KD 4
#define RR 6
#define NLAY 2
#define C4 (4*CC)     // 384
#define SLOTF 47424   // per-layer weight-slot stride in float units
#define STPW 2048     // scan: stored elems per wave (8 waves/block)
#define WARM 512      // scan: warm-up elems

typedef unsigned short u16;
typedef __attribute__((ext_vector_type(8))) short bf16x8;
typedef __attribute__((ext_vector_type(4))) float f32x4;
typedef __attribute__((ext_vector_type(2))) unsigned u32x2;
typedef __attribute__((ext_vector_type(4))) unsigned u32x4;

__device__ __forceinline__ u16 f2bf(float f){
  unsigned u = __float_as_uint(f);
  unsigned r = (u + 0x7FFFu + ((u >> 16) & 1u)) >> 16;
  return (u16)r;
}
__device__ __forceinline__ float bf2f(u16 h){
  return __uint_as_float(((unsigned)h) << 16);
}
__device__ __forceinline__ unsigned pk_bf16(float lo, float hi){
  unsigned r;
  asm volatile("v_cvt_pk_bf16_f32 %0, %1, %2" : "=v"(r) : "v"(lo), "v"(hi));
  return r;
}
__device__ __forceinline__ float fexp2(float x){
  float r; asm("v_exp_f32 %0, %1" : "=v"(r) : "v"(x)); return r;
}
__device__ __forceinline__ float flog2(float x){
  float r; asm("v_log_f32 %0, %1" : "=v"(r) : "v"(x)); return r;
}
// tanh-approx GELU, division-free
__device__ __forceinline__ float gelu_f(float v){
  float t = v*v;
  float u = v*fmaf(0.0356774081f, t, 0.7978845608f);
  float e2 = __expf(2.f*u);
  float r = __builtin_amdgcn_rcpf(e2 + 1.f);
  return fmaf(-v, r, v);
}

// ---------------- build batched input (bf16 plane) ----------------
__global__ void k_build(const float* __restrict__ x0, const float* __restrict__ x1,
                        u16* __restrict__ X){
  size_t i = (size_t)blockIdx.x*256 + threadIdx.x;
  size_t tot = (size_t)2*CC*HH*WW;
  if (i >= tot) return;
  int w = i % WW; size_t r = i / WW;
  int h = r % HH; size_t bc = r / HH;
  float val;
  if (w < 128) val = x0[(bc*HH + h)*128 + w];
  else         val = x1[(bc*HH + h)*128 + (w-128)];
  u16 hv = f2bf(val);
  X[i] = hv;
  size_t ib = ((bc + (size_t)2*CC)*HH + h)*WW + (WW-1-w);
  X[ib] = hv;
}

// ---------------- weight prep: swizzle into MFMA-fragment order ----------------
template<int M, int K, bool FC1ORD, bool LNF, bool BIAS>
__global__ void k_prepw(const float* __restrict__ W, const float* __restrict__ lnw,
      const float* __restrict__ lnb, const float* __restrict__ bias,
      u16* __restrict__ Wb, float* __restrict__ s1, float* __restrict__ cadd){
  int lay = blockIdx.y;
  W += (size_t)lay*M*K;
  Wb += (size_t)lay*SLOTF*2;
  s1 += (size_t)lay*SLOTF;
  cadd += (size_t)lay*SLOTF;
  int m = blockIdx.x*64 + threadIdx.x;
  if (m >= M) return;
  int rowfrag = m >> 4, lr = m & 15;
  float s1v = 0.f, sbv = 0.f;
  for (int c = 0; c < K; ++c){
    float wv = W[(size_t)m*K + c];
    float wf = LNF ? wv*lnw[lay*K + c] : wv;
    u16 h = f2bf(wf);
    int colfrag = c >> 5, lg = (c >> 3) & 3, j = c & 7;
    int f;
    if (FC1ORD) f = (rowfrag/6)*18 + colfrag*6 + (rowfrag % 6);
    else        f = colfrag*(M/16) + rowfrag;
    Wb[(size_t)(f*64 + lg*16 + lr)*8 + j] = h;
    s1v += bf2f(h);
    if (LNF) sbv = fmaf(wv, lnb[lay*K + c], sbv);
  }
  if (BIAS) sbv += bias[lay*M + m];
  s1[m] = s1v;
  cadd[m] = sbv;
}

// ---------------- projection GEMM (M=96,K=96), plane-major bf16 in/out ----------------
template<bool RES>
__global__ __launch_bounds__(256) void k_proj(
    const u16* __restrict__ Wb, const u16* __restrict__ inP,
    u16* __restrict__ outP, const u16* __restrict__ resP,
    const float* __restrict__ s1v, const float* __restrict__ cadd){
  __shared__ u16 bt[128*104];
  __shared__ float sA[2][128], sB[2][128], sm[128], sr[128];
  int tid = threadIdx.x, lane = tid & 63, wid = tid >> 6;
  int l0 = blockIdx.x*128;
  int b = l0 >> 14, lb0 = l0 & (LL-1);
  int lr = lane & 15, lg = lane >> 4;
  {
    int px = tid & 127, grp = tid >> 7;
    int ch0 = grp*48;
    const u16* ip = inP + ((size_t)b*CC + ch0)*LL + lb0 + px;
    u16 ch[48];
    float s = 0.f, ss = 0.f;
    #pragma unroll
    for (int j = 0; j < 48; ++j){
      ch[j] = ip[(size_t)j*LL];
      float xv = bf2f(ch[j]);
      s += xv; ss += xv*xv;
    }
    #pragma unroll
    for (int j2 = 0; j2 < 12; ++j2){
      uint2 w2;
      w2.x = (unsigned)ch[j2*4+0] | ((unsigned)ch[j2*4+1] << 16);
      w2.y = (unsigned)ch[j2*4+2] | ((unsigned)ch[j2*4+3] << 16);
      *(uint2*)&bt[px*104 + ch0 + j2*4] = w2;
    }
    sA[grp][px] = s;
    sB[grp][px] = ss;
  }
  __syncthreads();
  if (tid < 128){
    float s = sA[0][tid] + sA[1][tid];
    float ss = sB[0][tid] + sB[1][tid];
    float mu = s*(1.f/CC);
    float var = ss*(1.f/CC) - mu*mu;
    sm[tid] = mu;
    sr[tid] = rsqrtf(var + 1e-5f);
  }
  f32x4 acc[6][2];
  #pragma unroll
  for (int mf = 0; mf < 6; ++mf){ acc[mf][0] = (f32x4){0,0,0,0}; acc[mf][1] = (f32x4){0,0,0,0}; }
  #pragma unroll
  for (int ks = 0; ks < 3; ++ks){
    bf16x8 af[6];
    #pragma unroll
    for (int mf = 0; mf < 6; ++mf)
      af[mf] = *(const bf16x8*)(Wb + (size_t)((ks*6 + mf)*64 + lane)*8);
    bf16x8 bfr[2];
    #pragma unroll
    for (int ls = 0; ls < 2; ++ls)
      bfr[ls] = *(const bf16x8*)&bt[(wid*32 + ls*16 + lr)*104 + ks*32 + lg*8];
    #pragma unroll
    for (int mf = 0; mf < 6; ++mf)
      #pragma unroll
      for (int ls = 0; ls < 2; ++ls)
        acc[mf][ls] = __builtin_amdgcn_mfma_f32_16x16x32_bf16(af[mf], bfr[ls], acc[mf][ls], 0, 0, 0);
  }
  __syncthreads();   // sm/sr ready
  #pragma unroll
  for (int ls = 0; ls < 2; ++ls){
    int row = wid*32 + ls*16 + lr;
    float mu = sm[row], rs = sr[row];
    float nmr = -mu*rs;
    #pragma unroll
    for (int mf = 0; mf < 6; ++mf){
      #pragma unroll
      for (int r = 0; r < 4; ++r){
        int mm = mf*16 + lg*4 + r;
        float vv = fmaf(rs, acc[mf][ls][r], fmaf(nmr, s1v[mm], cadd[mm]));
        size_t idx = ((size_t)b*CC + mm)*LL + lb0 + row;
        if (RES){
          vv += bf2f(resP[idx]);
          outP[idx] = f2bf(vv);
        } else {
          __builtin_nontemporal_store(f2bf(vv), &outP[idx]);
        }
      }
    }
  }
}

// ---------------- fused MLP v5: plane-major bf16 io, in-kernel stats ----------------
__global__ __launch_bounds__(512, 4) void k_mlp(
    const u16* __restrict__ Wb1, const u16* __restrict__ Wb2,
    u16* __restrict__ X,
    const float* __restrict__ s11, const float* __restrict__ c1,
    const float* __restrict__ c2){
  __shared__ u16 bt[128*104];
  __shared__ u16 hs[128*104];
  __shared__ float sm[128], sr[128];
  float* sA = (float*)hs;
  float* sB = sA + 512;
  int tid = threadIdx.x, lane = tid & 63, wid = tid >> 6;
  int l0 = blockIdx.x*128;
  int b = l0 >> 14, lb0 = l0 & (LL-1);
  int lr = lane & 15, lg = lane >> 4;
  {
    int px = tid & 127, grp = tid >> 7;
    int ch0 = grp*24;
    const u16* ip = X + ((size_t)b*CC + ch0)*LL + lb0 + px;
    u16 ch[24];
    float s = 0.f, ss = 0.f;
    #pragma unroll
    for (int j = 0; j < 24; ++j){
      ch[j] = ip[(size_t)j*LL];
      float xv = bf2f(ch[j]);
      s += xv; ss += xv*xv;
    }
    #pragma unroll
    for (int j2 = 0; j2 < 6; ++j2){
      uint2 w2;
      w2.x = (unsigned)ch[j2*4+0] | ((unsigned)ch[j2*4+1] << 16);
      w2.y = (unsigned)ch[j2*4+2] | ((unsigned)ch[j2*4+3] << 16);
      *(uint2*)&bt[px*104 + ch0 + j2*4] = w2;
    }
    sA[grp*128 + px] = s;
    sB[grp*128 + px] = ss;
  }
  __syncthreads();
  if (tid < 128){
    float s = sA[tid] + sA[128+tid] + sA[256+tid] + sA[384+tid];
    float ss = sB[tid] + sB[128+tid] + sB[256+tid] + sB[384+tid];
    float mu = s*(1.f/CC);
    float var = ss*(1.f/CC) - mu*mu;
    sm[tid] = mu;
    sr[tid] = rsqrtf(var + 1e-5f);
  }
  __syncthreads();
  int row = wid*16 + lr;
  float rs = sr[row];
  float nmr = -sm[row]*rs;

  int hrow = row*104;
  f32x4 acc2[6];
  #pragma unroll
  for (int mf = 0; mf < 6; ++mf) acc2[mf] = (f32x4){0,0,0,0};

  for (int cc = 0; cc < 4; ++cc){
    f32x4 acc1[6];
    #pragma unroll
    for (int mf = 0; mf < 6; ++mf) acc1[mf] = (f32x4){0,0,0,0};
    #pragma unroll
    for (int ks = 0; ks < 3; ++ks){
      bf16x8 af[6];
      #pragma unroll
      for (int mf = 0; mf < 6; ++mf)
        af[mf] = *(const bf16x8*)(Wb1 + (size_t)((cc*18 + ks*6 + mf)*64 + lane)*8);
      bf16x8 bfr = *(const bf16x8*)&bt[hrow + ks*32 + lg*8];
      #pragma unroll
      for (int mf = 0; mf < 6; ++mf)
        acc1[mf] = __builtin_amdgcn_mfma_f32_16x16x32_bf16(af[mf], bfr, acc1[mf], 0, 0, 0);
    }
    #pragma unroll
    for (int mf = 0; mf < 6; ++mf){
      float4 sv = *(const float4*)&s11[cc*96 + mf*16 + lg*4];
      float4 cv = *(const float4*)&c1 [cc*96 + mf*16 + lg*4];
      float g0 = gelu_f(fmaf(rs, acc1[mf][0], fmaf(nmr, sv.x, cv.x)));
      float g1 = gelu_f(fmaf(rs, acc1[mf][1], fmaf(nmr, sv.y, cv.y)));
      float g2 = gelu_f(fmaf(rs, acc1[mf][2], fmaf(nmr, sv.z, cv.z)));
      float g3 = gelu_f(fmaf(rs, acc1[mf][3], fmaf(nmr, sv.w, cv.w)));
      uint2 pw;
      pw.x = pk_bf16(g0, g1);
      pw.y = pk_bf16(g2, g3);
      *(uint2*)&hs[hrow + mf*16 + lg*4] = pw;
    }
    #pragma unroll
    for (int ks = 0; ks < 3; ++ks){
      bf16x8 a2[6];
      #pragma unroll
      for (int mf2 = 0; mf2 < 6; ++mf2)
        a2[mf2] = *(const bf16x8*)(Wb2 + (size_t)(((cc*3 + ks)*6 + mf2)*64 + lane)*8);
      bf16x8 bfr2 = *(const bf16x8*)&hs[hrow + ks*32 + lg*8];
      #pragma unroll
      for (int mf2 = 0; mf2 < 6; ++mf2)
        acc2[mf2] = __builtin_amdgcn_mfma_f32_16x16x32_bf16(a2[mf2], bfr2, acc2[mf2], 0, 0, 0);
    }
  }
  #pragma unroll
  for (int mf = 0; mf < 6; ++mf){
    #pragma unroll
    for (int r = 0; r < 4; ++r){
      int mm = mf*16 + lg*4 + r;
      size_t idx = ((size_t)b*CC + mm)*LL + lb0 + row;
      float vv = acc2[mf][r] + c2[mm] + bf2f(X[idx]);
      X[idx] = f2bf(vv);
    }
  }
}

// ---------------- depthwise 3x3 + SiLU (bf16 in/out), fused transpose ----------------
__global__ __launch_bounds__(256) void k_dwconv_silu_t(const u16* __restrict__ u,
      u16* __restrict__ v, u16* __restrict__ vT, const float* __restrict__ cw){
  __shared__ float tl[32][33];
  int bc = blockIdx.z;
  int c = bc % CC;
  int w0 = blockIdx.x*32, h0 = blockIdx.y*32;
  const u16* up = u + (size_t)bc*LL;
  const float* k9 = cw + c*9;
  int t = threadIdx.x;
  int wl = (t & 7)*4, hl = t >> 3;
  int h = h0 + hl, w = w0 + wl;
  float acc[4] = {0.f,0.f,0.f,0.f};
  #pragma unroll
  for (int dh = -1; dh <= 1; ++dh){
    int h2 = h + dh;
    if (h2 < 0 || h2 >= HH) continue;
    const u16* row = up + (size_t)h2*WW + w;
    ushort4 mq = *(const ushort4*)row;
    float m0 = bf2f(mq.x), m1 = bf2f(mq.y), m2 = bf2f(mq.z), m3 = bf2f(mq.w);
    float lft = (w > 0) ? bf2f(row[-1]) : 0.f;
    float rgt = (w + 4 < WW) ? bf2f(row[4]) : 0.f;
    float k0 = k9[(dh+1)*3], k1 = k9[(dh+1)*3+1], k2 = k9[(dh+1)*3+2];
    acc[0] += lft*k0 + m0*k1 + m1*k2;
    acc[1] += m0*k0 + m1*k1 + m2*k2;
    acc[2] += m1*k0 + m2*k1 + m3*k2;
    acc[3] += m2*k0 + m3*k1 + rgt*k2;
  }
  float s[4];
  #pragma unroll
  for (int j = 0; j < 4; ++j){
    float a = acc[j];
    float e = __expf(-a);
    s[j] = a * __builtin_amdgcn_rcpf(1.f + e);
    tl[wl + j][hl] = s[j];
  }
  u32x2 pw;
  pw.x = pk_bf16(s[0], s[1]);
  pw.y = pk_bf16(s[2], s[3]);
  __builtin_nontemporal_store(pw, (u32x2*)&v[(size_t)bc*LL + (size_t)h*WW + w]);
  __syncthreads();
  int ww = t >> 3, hh4 = (t & 7)*4;
  u32x2 po;
  po.x = pk_bf16(tl[ww][hh4],   tl[ww][hh4+1]);
  po.y = pk_bf16(tl[ww][hh4+2], tl[ww][hh4+3]);
  __builtin_nontemporal_store(po, (u32x2*)&vT[(size_t)bc*LL + (size_t)(w0 + ww)*HH + h0 + hh4]);
}

// ---------------- x-projection (bf16 src, bf16 G out) ----------------
__global__ void k_xproj(const u16* __restrict__ v, const u16* __restrict__ vT,
                        u16* __restrict__ G, const float* __restrict__ xpw){
  int which = blockIdx.y;
  const u16* src = which ? vT : v;
  int kA = which ? 1 : 0, kB = which ? 3 : 2;
  size_t i = (size_t)blockIdx.x*256 + threadIdx.x;
  if (i >= (size_t)BT*LL) return;
  int b = (int)(i / LL), l = (int)(i % LL);
  const u16* sp = src + (size_t)b*CC*LL + l;
  const float* wA = xpw + (size_t)kA*8*CC;
  const float* wB = xpw + (size_t)kB*8*CC;
  float aA[8], aB[8];
  #pragma unroll
  for (int d = 0; d < 8; ++d){ aA[d] = 0.f; aB[d] = 0.f; }
  for (int c = 0; c < CC; ++c){
    float xv = bf2f(sp[(size_t)c*LL]);
    #pragma unroll
    for (int d = 0; d < 8; ++d){
      aA[d] = fmaf(wA[d*CC + c], xv, aA[d]);
      aB[d] = fmaf(wB[d*CC + c], xv, aB[d]);
    }
  }
  u16* gA = G + (((size_t)b*KD + kA)*8)*LL + l;
  u16* gB = G + (((size_t)b*KD + kB)*8)*LL + l;
  #pragma unroll
  for (int d = 0; d < 8; ++d){
    __builtin_nontemporal_store(f2bf(aA[d]), &gA[(size_t)d*LL]);
    __builtin_nontemporal_store(f2bf(aB[d]), &gB[(size_t)d*LL]);
  }
}

// ---------------- scan v7: single-chain, 8 waves/block, bf16, NT stores ----------------
__device__ __forceinline__ void ldbf8(const u16* p, float* o){
  uint4 t = *(const uint4*)p;
  o[0]=bf2f((u16)(t.x & 0xffff)); o[1]=bf2f((u16)(t.x >> 16));
  o[2]=bf2f((u16)(t.y & 0xffff)); o[3]=bf2f((u16)(t.y >> 16));
  o[4]=bf2f((u16)(t.z & 0xffff)); o[5]=bf2f((u16)(t.z >> 16));
  o[6]=bf2f((u16)(t.w & 0xffff)); o[7]=bf2f((u16)(t.w >> 16));
}
__device__ __forceinline__ void rev8(float* a){
  #pragma unroll
  for (int i = 0; i < 4; ++i){ float t0 = a[i]; a[i] = a[7-i]; a[7-i] = t0; }
}

__global__ __launch_bounds__(512) void k_scan3(const u16* __restrict__ G,
                       const u16* __restrict__ v, const u16* __restrict__ vT,
                       u16* __restrict__ Y,
                       const float* __restrict__ dtw_, const float* __restrict__ dtb_,
                       const float* __restrict__ Alog_, const float* __restrict__ Ds_){
  const size_t SZ = (size_t)BT*CC*LL;
  const float LOG2E = 1.4426950408889634f, LN2 = 0.6931471805599453f;
  int wid = threadIdx.x >> 6, lane = threadIdx.x & 63;
  int tile = wid;                              // 0..7 (8 tiles x 2048 = 16384)
  int sy = blockIdx.y;
  bool rev = (blockIdx.z != 0);
  int c = sy % CC; int t2 = sy / CC; int kk = t2 & 1; int b = t2 >> 1;
  int k = (rev ? 2 : 0) + kk;
  const u16* src = (kk ? vT : v) + ((size_t)b*CC + c)*LL;
  const u16* g = G + (((size_t)b*KD + k)*8)*LL;
  float dtw[RR];
  #pragma unroll
  for (int r = 0; r < RR; ++r) dtw[r] = dtw_[((size_t)k*CC + c)*RR + r];
  float dtb = dtb_[k*CC + c];
  float A  = -__expf(Alog_[k*CC + c]);
  float Dv = Ds_[k*CC + c];
  u16* yout = Y + (size_t)k*SZ + ((size_t)b*CC + c)*LL;

  int lstore0 = tile*STPW;
  float carry = 0.f;
  for (int p = 0; p < 1 + STPW/WARM; ++p){
    int base = lstore0 - WARM + p*WARM;
    if (base < 0) continue;                    // tile 0: no warm-up
    bool st = (base >= lstore0);
    int l = base + (lane<<3);
    int ga = rev ? (LL-8-l) : l;
    float dsum[8], g6b[8], g7b[8], xb[8];
    #pragma unroll
    for (int i = 0; i < 8; ++i) dsum[i] = dtb;
    #pragma unroll
    for (int r = 0; r < RR; ++r){
      float t8[8];
      ldbf8(g + (size_t)r*LL + ga, t8);
      #pragma unroll
      for (int i = 0; i < 8; ++i) dsum[i] = fmaf(t8[i], dtw[r], dsum[i]);
    }
    ldbf8(g + (size_t)6*LL + ga, g6b);
    if (st){
      ldbf8(g + (size_t)7*LL + ga, g7b);
    } else {
      #pragma unroll
      for (int i = 0; i < 8; ++i) g7b[i] = 0.f;
    }
    ldbf8(src + ga, xb);
    if (rev){ rev8(dsum); rev8(g6b); rev8(g7b); rev8(xb); }
    float av[8], bt[8];
    #pragma unroll
    for (int i = 0; i < 8; ++i){
      float dl2 = dsum[i]*LOG2E;
      float y = flog2(1.f + fexp2(dl2));
      y = (dsum[i] > 20.f) ? dl2 : y;
      float delta = y*LN2;
      av[i] = fexp2(A*y);
      bt[i] = delta * g6b[i] * xb[i];
    }
    float P = av[0], Q = bt[0];
    #pragma unroll
    for (int i = 1; i < 8; ++i){ Q = fmaf(av[i], Q, bt[i]); P *= av[i]; }
    #pragma unroll
    for (int off = 1; off < 64; off <<= 1){
      float Pp = __shfl_up(P, (unsigned)off);
      float Qp = __shfl_up(Q, (unsigned)off);
      if (lane >= off){ Q = fmaf(P, Qp, Q); P *= Pp; }
    }
    float Pe = __shfl_up(P, 1u), Qe = __shfl_up(Q, 1u);
    if (lane == 0){ Pe = 1.f; Qe = 0.f; }
    float h = fmaf(Pe, carry, Qe);
    if (st){
      float ys[8];
      #pragma unroll
      for (int i = 0; i < 8; ++i){
        h = fmaf(av[i], h, bt[i]);
        ys[i] = fmaf(g7b[i], h, Dv*xb[i]);
      }
      carry = __shfl(h, 63);
      if (rev) rev8(ys);
      u32x4 pw;
      pw.x = pk_bf16(ys[0], ys[1]);
      pw.y = pk_bf16(ys[2], ys[3]);
      pw.z = pk_bf16(ys[4], ys[5]);
      pw.w = pk_bf16(ys[6], ys[7]);
      __builtin_nontemporal_store(pw, (u32x4*)&yout[ga]);
    } else {
      #pragma unroll
      for (int i = 0; i < 8; ++i) h = fmaf(av[i], h, bt[i]);
      carry = __shfl(h, 63);
    }
  }
}

// ---------------- combine (bf16 in/out): z = (y0+y2) + transpose(y1+y3) ----------------
__global__ __launch_bounds__(256) void k_combine4(const u16* __restrict__ Y, u16* __restrict__ z){
  const size_t SZ = (size_t)BT*CC*LL;
  __shared__ float tl[64][65];
  int bc = blockIdx.z;
  int w0 = blockIdx.x*64;
  int t = threadIdx.x;
  const u16* y1p = Y + SZ   + (size_t)bc*LL;
  const u16* y3p = Y + 3*SZ + (size_t)bc*LL;
  {
    int wl = t >> 2;            // 0..63
    int h0 = (t & 3)*16;        // 0,16,32,48
    size_t base = (size_t)(w0 + wl)*HH + h0;
    #pragma unroll
    for (int j = 0; j < 4; ++j){
      u32x2 a = __builtin_nontemporal_load((const u32x2*)&y1p[base + j*4]);
      u32x2 bq = __builtin_nontemporal_load((const u32x2*)&y3p[base + j*4]);
      tl[wl][h0 + j*4 + 0] = bf2f((u16)(a.x & 0xffff)) + bf2f((u16)(bq.x & 0xffff));
      tl[wl][h0 + j*4 + 1] = bf2f((u16)(a.x >> 16))    + bf2f((u16)(bq.x >> 16));
      tl[wl][h0 + j*4 + 2] = bf2f((u16)(a.y & 0xffff)) + bf2f((u16)(bq.y & 0xffff));
      tl[wl][h0 + j*4 + 3] = bf2f((u16)(a.y >> 16))    + bf2f((u16)(bq.y >> 16));
    }
  }
  __syncthreads();
  const u16* y0p = Y +        (size_t)bc*LL;
  const u16* y2p = Y + 2*SZ + (size_t)bc*LL;
  u16* zp = z + (size_t)bc*LL;
  {
    int h = t >> 2;             // 0..63
    int wq = (t & 3)*16;        // 0,16,32,48
    #pragma unroll
    for (int j = 0; j < 4; ++j){
      int wl = wq + j*4;
      size_t idx = (size_t)h*WW + w0 + wl;
      u32x2 a = __builtin_nontemporal_load((const u32x2*)&y0p[idx]);
      u32x2 bq = __builtin_nontemporal_load((const u32x2*)&y2p[idx]);
      float v0 = bf2f((u16)(a.x & 0xffff)) + bf2f((u16)(bq.x & 0xffff)) + tl[wl+0][h];
      float v1 = bf2f((u16)(a.x >> 16))    + bf2f((u16)(bq.x >> 16))    + tl[wl+1][h];
      float v2 = bf2f((u16)(a.y & 0xffff)) + bf2f((u16)(bq.y & 0xffff)) + tl[wl+2][h];
      float v3 = bf2f((u16)(a.y >> 16))    + bf2f((u16)(bq.y >> 16))    + tl[wl+3][h];
      u32x2 o;
      o.x = pk_bf16(v0, v1);
      o.y = pk_bf16(v2, v3);
      __builtin_nontemporal_store(o, (u32x2*)&zp[idx]);
    }
  }
}

// ---------------- final output split/average (bf16 X -> f32 out) ----------------
__global__ void k_output(const u16* __restrict__ X, float* __restrict__ out){
  size_t i = (size_t)blockIdx.x*256 + threadIdx.x;
  size_t half = (size_t)2*CC*HH*128;
  if (i >= half) return;
  int w = i % 128; size_t r = i / 128;
  int h = r % HH; size_t bc = r / HH;
  size_t fwd = (bc*HH + h)*WW;
  size_t bwd = ((bc + (size_t)2*CC)*HH + h)*WW;
  float o0 = 0.5f*(bf2f(X[fwd + w])       + bf2f(X[bwd + (WW-1-w)]));
  float o1 = 0.5f*(bf2f(X[fwd + 128 + w]) + bf2f(X[bwd + (127 - w)]));
  __builtin_nontemporal_store(o0, &out[i]);
  __builtin_nontemporal_store(o1, &out[half + i]);
}

extern "C" void kernel_launch(void* const* d_in, const int* in_sizes, int n_in,
                              void* d_out, int out_size, void* d_ws, size_t ws_size,
                              hipStream_t stream){
  const float* x0        = (const float*)d_in[0];
  const float* x1        = (const float*)d_in[1];
  const float* norm_w    = (const float*)d_in[2];
  const float* norm_b    = (const float*)d_in[3];
  const float* in_proj_w = (const float*)d_in[4];
  const float* conv_w    = (const float*)d_in[5];
  const float* x_proj_w  = (const float*)d_in[6];
  const float* dt_w      = (const float*)d_in[7];
  const float* dt_b      = (const float*)d_in[8];
  const float* A_logs    = (const float*)d_in[9];
  const float* Ds        = (const float*)d_in[10];
  const float* out_norm_w= (const float*)d_in[11];
  const float* out_norm_b= (const float*)d_in[12];
  const float* out_proj_w= (const float*)d_in[13];
  const float* norm2_w   = (const float*)d_in[14];
  const float* norm2_b   = (const float*)d_in[15];
  const float* fc1_w     = (const float*)d_in[16];
  const float* fc1_b     = (const float*)d_in[17];
  const float* fc2_w     = (const float*)d_in[18];
  const float* fc2_b     = (const float*)d_in[19];

  const size_t SZ = (size_t)BT*CC*LL;            // 6,291,456 elems
  u16* Xb  = (u16*)d_ws;
  u16* tB  = Xb + SZ;
  u16* uB  = tB + SZ;
  u16* vB  = uB + SZ;
  u16* vTB = vB + SZ;
  u16* Gb  = vTB + SZ;                           // BT*KD*8*LL u16
  u16* Yb  = Gb + (size_t)BT*KD*8*LL;            // 4*SZ u16
  float* wsl = (float*)(Yb + 4*SZ);              // weight slots

  float* p0 = wsl;
  u16*  WbI0 = (u16*)p0;          float* s1I0 = p0 + 4608;  float* cI0 = p0 + 4704;
  u16*  WbO0 = (u16*)(p0+4800);   float* s1O0 = p0 + 9408;  float* cO0 = p0 + 9504;
  u16*  Wb10 = (u16*)(p0+9600);   float* s110 = p0 + 28032; float* c10 = p0 + 28416;
  u16*  Wb20 = (u16*)(p0+28800);  float* s120 = p0 + 47232; float* c20 = p0 + 47328;

  k_prepw<96,96,false,true,false><<<dim3(2,NLAY),64,0,stream>>>(in_proj_w, norm_w, norm_b, nullptr, WbI0, s1I0, cI0);
  k_prepw<96,96,false,true,false><<<dim3(2,NLAY),64,0,stream>>>(out_proj_w, out_norm_w, out_norm_b, nullptr, WbO0, s1O0, cO0);
  k_prepw<384,96,true,true,true><<<dim3(6,NLAY),64,0,stream>>>(fc1_w, norm2_w, norm2_b, fc1_b, Wb10, s110, c10);
  k_prepw<96,384,false,false,true><<<dim3(2,NLAY),64,0,stream>>>(fc2_w, nullptr, nullptr, fc2_b, Wb20, s120, c20);

  k_build<<<(2*CC*HH*WW + 255)/256, 256, 0, stream>>>(x0, x1, Xb);

  for (int lay = 0; lay < NLAY; ++lay){
    size_t so = (size_t)lay*SLOTF;
    const u16* WbI = WbI0 + so*2; const float* s1I = s1I0 + so; const float* cI = cI0 + so;
    const u16* WbO = WbO0 + so*2; const float* s1O = s1O0 + so; const float* cO = cO0 + so;
    const u16* Wb1 = Wb10 + so*2; const float* s11 = s110 + so; const float* c1 = c10 + so;
    const u16* Wb2 = Wb20 + so*2; const float* c2 = c20 + so;
    const float* cw  = conv_w    + (size_t)lay*CC*9;
    const float* xpw = x_proj_w  + (size_t)lay*KD*8*CC;
    const float* dw  = dt_w      + (size_t)lay*KD*CC*RR;
    const float* db  = dt_b      + (size_t)lay*KD*CC;
    const float* Al  = A_logs    + (size_t)lay*KD*CC;
    const float* Dp  = Ds        + (size_t)lay*KD*CC;

    k_proj<false><<<dim3(BT*LL/128),256,0,stream>>>(WbI, Xb, uB, nullptr, s1I, cI);
    k_dwconv_silu_t<<<dim3(8,2,BT*CC), 256, 0, stream>>>(uB, vB, vTB, cw);
    k_xproj<<<dim3(BT*LL/256, 2), 256, 0, stream>>>(vB, vTB, Gb, xpw);
    k_scan3<<<dim3(1,768,2), 512, 0, stream>>>(Gb, vB, vTB, Yb, dw, db, Al, Dp);
    k_combine4<<<dim3(4,1,BT*CC), 256, 0, stream>>>(Yb, tB);
    k_proj<true><<<dim3(BT*LL/128),256,0,stream>>>(WbO, tB, Xb, Xb, s1O, cO);
    k_mlp<<<dim3(BT*LL/128),512,0,stream>>>(Wb1, Wb2, Xb, s11, c1, c2);
  }

  k_output<<<(unsigned)(((size_t)2*CC*HH*128 + 255)/256), 256, 0, stream>>>(Xb, (float*)d_out);
}

// Round 20
// 361.149 us; speedup vs baseline: 1.2355x; 1.2355x over previous
//
#include <hip/hip_runtime.h>
#include <cstdint>
#include <cstddef>

#define BT 4
#define CC 96
#define HH 64
#define WW 256
#define LL (HH*WW)    // 16384
#define KD 4
#define RR 6
#define NLAY 2
#define C4 (4*CC)     // 384
#define SLOTF 47424   // per-layer weight-slot stride in float units
#define STPW 2048     // scan: stored elems per wave (8 waves/block)
#define WARM 512      // scan: warm-up elems

typedef unsigned short u16;
typedef __attribute__((ext_vector_type(8))) short bf16x8;
typedef __attribute__((ext_vector_type(4))) float f32x4;

__device__ __forceinline__ u16 f2bf(float f){
  unsigned u = __float_as_uint(f);
  unsigned r = (u + 0x7FFFu + ((u >> 16) & 1u)) >> 16;
  return (u16)r;
}
__device__ __forceinline__ float bf2f(u16 h){
  return __uint_as_float(((unsigned)h) << 16);
}
__device__ __forceinline__ unsigned pk_bf16(float lo, float hi){
  unsigned r;
  asm volatile("v_cvt_pk_bf16_f32 %0, %1, %2" : "=v"(r) : "v"(lo), "v"(hi));
  return r;
}
__device__ __forceinline__ float fexp2(float x){
  float r; asm("v_exp_f32 %0, %1" : "=v"(r) : "v"(x)); return r;
}
__device__ __forceinline__ float flog2(float x){
  float r; asm("v_log_f32 %0, %1" : "=v"(r) : "v"(x)); return r;
}
// tanh-approx GELU, division-free
__device__ __forceinline__ float gelu_f(float v){
  float t = v*v;
  float u = v*fmaf(0.0356774081f, t, 0.7978845608f);
  float e2 = __expf(2.f*u);
  float r = __builtin_amdgcn_rcpf(e2 + 1.f);
  return fmaf(-v, r, v);
}

// ---------------- build batched input (bf16 plane) ----------------
__global__ void k_build(const float* __restrict__ x0, const float* __restrict__ x1,
                        u16* __restrict__ X){
  size_t i = (size_t)blockIdx.x*256 + threadIdx.x;
  size_t tot = (size_t)2*CC*HH*WW;
  if (i >= tot) return;
  int w = i % WW; size_t r = i / WW;
  int h = r % HH; size_t bc = r / HH;
  float val;
  if (w < 128) val = x0[(bc*HH + h)*128 + w];
  else         val = x1[(bc*HH + h)*128 + (w-128)];
  u16 hv = f2bf(val);
  X[i] = hv;
  size_t ib = ((bc + (size_t)2*CC)*HH + h)*WW + (WW-1-w);
  X[ib] = hv;
}

// ---------------- weight prep: swizzle into MFMA-fragment order ----------------
template<int M, int K, bool FC1ORD, bool LNF, bool BIAS>
__global__ void k_prepw(const float* __restrict__ W, const float* __restrict__ lnw,
      const float* __restrict__ lnb, const float* __restrict__ bias,
      u16* __restrict__ Wb, float* __restrict__ s1, float* __restrict__ cadd){
  int lay = blockIdx.y;
  W += (size_t)lay*M*K;
  Wb += (size_t)lay*SLOTF*2;
  s1 += (size_t)lay*SLOTF;
  cadd += (size_t)lay*SLOTF;
  int m = blockIdx.x*64 + threadIdx.x;
  if (m >= M) return;
  int rowfrag = m >> 4, lr = m & 15;
  float s1v = 0.f, sbv = 0.f;
  for (int c = 0; c < K; ++c){
    float wv = W[(size_t)m*K + c];
    float wf = LNF ? wv*lnw[lay*K + c] : wv;
    u16 h = f2bf(wf);
    int colfrag = c >> 5, lg = (c >> 3) & 3, j = c & 7;
    int f;
    if (FC1ORD) f = (rowfrag/6)*18 + colfrag*6 + (rowfrag % 6);
    else        f = colfrag*(M/16) + rowfrag;
    Wb[(size_t)(f*64 + lg*16 + lr)*8 + j] = h;
    s1v += bf2f(h);
    if (LNF) sbv = fmaf(wv, lnb[lay*K + c], sbv);
  }
  if (BIAS) sbv += bias[lay*M + m];
  s1[m] = s1v;
  cadd[m] = sbv;
}

// ---------------- projection GEMM (M=96,K=96), plane-major bf16 in/out ----------------
template<bool RES>
__global__ __launch_bounds__(256) void k_proj(
    const u16* __restrict__ Wb, const u16* __restrict__ inP,
    u16* __restrict__ outP, const u16* __restrict__ resP,
    const float* __restrict__ s1v, const float* __restrict__ cadd){
  __shared__ u16 bt[128*104];
  __shared__ float sA[2][128], sB[2][128], sm[128], sr[128];
  int tid = threadIdx.x, lane = tid & 63, wid = tid >> 6;
  int l0 = blockIdx.x*128;
  int b = l0 >> 14, lb0 = l0 & (LL-1);
  int lr = lane & 15, lg = lane >> 4;
  {
    int px = tid & 127, grp = tid >> 7;
    int ch0 = grp*48;
    const u16* ip = inP + ((size_t)b*CC + ch0)*LL + lb0 + px;
    u16 ch[48];
    float s = 0.f, ss = 0.f;
    #pragma unroll
    for (int j = 0; j < 48; ++j){
      ch[j] = ip[(size_t)j*LL];
      float xv = bf2f(ch[j]);
      s += xv; ss += xv*xv;
    }
    #pragma unroll
    for (int j2 = 0; j2 < 12; ++j2){
      uint2 w2;
      w2.x = (unsigned)ch[j2*4+0] | ((unsigned)ch[j2*4+1] << 16);
      w2.y = (unsigned)ch[j2*4+2] | ((unsigned)ch[j2*4+3] << 16);
      *(uint2*)&bt[px*104 + ch0 + j2*4] = w2;
    }
    sA[grp][px] = s;
    sB[grp][px] = ss;
  }
  __syncthreads();
  if (tid < 128){
    float s = sA[0][tid] + sA[1][tid];
    float ss = sB[0][tid] + sB[1][tid];
    float mu = s*(1.f/CC);
    float var = ss*(1.f/CC) - mu*mu;
    sm[tid] = mu;
    sr[tid] = rsqrtf(var + 1e-5f);
  }
  f32x4 acc[6][2];
  #pragma unroll
  for (int mf = 0; mf < 6; ++mf){ acc[mf][0] = (f32x4){0,0,0,0}; acc[mf][1] = (f32x4){0,0,0,0}; }
  #pragma unroll
  for (int ks = 0; ks < 3; ++ks){
    bf16x8 af[6];
    #pragma unroll
    for (int mf = 0; mf < 6; ++mf)
      af[mf] = *(const bf16x8*)(Wb + (size_t)((ks*6 + mf)*64 + lane)*8);
    bf16x8 bfr[2];
    #pragma unroll
    for (int ls = 0; ls < 2; ++ls)
      bfr[ls] = *(const bf16x8*)&bt[(wid*32 + ls*16 + lr)*104 + ks*32 + lg*8];
    #pragma unroll
    for (int mf = 0; mf < 6; ++mf)
      #pragma unroll
      for (int ls = 0; ls < 2; ++ls)
        acc[mf][ls] = __builtin_amdgcn_mfma_f32_16x16x32_bf16(af[mf], bfr[ls], acc[mf][ls], 0, 0, 0);
  }
  __syncthreads();   // sm/sr ready
  #pragma unroll
  for (int ls = 0; ls < 2; ++ls){
    int row = wid*32 + ls*16 + lr;
    float mu = sm[row], rs = sr[row];
    float nmr = -mu*rs;
    #pragma unroll
    for (int mf = 0; mf < 6; ++mf){
      #pragma unroll
      for (int r = 0; r < 4; ++r){
        int mm = mf*16 + lg*4 + r;
        float vv = fmaf(rs, acc[mf][ls][r], fmaf(nmr, s1v[mm], cadd[mm]));
        size_t idx = ((size_t)b*CC + mm)*LL + lb0 + row;
        if (RES) vv += bf2f(resP[idx]);
        outP[idx] = f2bf(vv);
      }
    }
  }
}

// ---------------- fused MLP v5: plane-major bf16 io, in-kernel stats ----------------
__global__ __launch_bounds__(512, 4) void k_mlp(
    const u16* __restrict__ Wb1, const u16* __restrict__ Wb2,
    u16* __restrict__ X,
    const float* __restrict__ s11, const float* __restrict__ c1,
    const float* __restrict__ c2){
  __shared__ u16 bt[128*104];
  __shared__ u16 hs[128*104];
  __shared__ float sm[128], sr[128];
  float* sA = (float*)hs;
  float* sB = sA + 512;
  int tid = threadIdx.x, lane = tid & 63, wid = tid >> 6;
  int l0 = blockIdx.x*128;
  int b = l0 >> 14, lb0 = l0 & (LL-1);
  int lr = lane & 15, lg = lane >> 4;
  {
    int px = tid & 127, grp = tid >> 7;
    int ch0 = grp*24;
    const u16* ip = X + ((size_t)b*CC + ch0)*LL + lb0 + px;
    u16 ch[24];
    float s = 0.f, ss = 0.f;
    #pragma unroll
    for (int j = 0; j < 24; ++j){
      ch[j] = ip[(size_t)j*LL];
      float xv = bf2f(ch[j]);
      s += xv; ss += xv*xv;
    }
    #pragma unroll
    for (int j2 = 0; j2 < 6; ++j2){
      uint2 w2;
      w2.x = (unsigned)ch[j2*4+0] | ((unsigned)ch[j2*4+1] << 16);
      w2.y = (unsigned)ch[j2*4+2] | ((unsigned)ch[j2*4+3] << 16);
      *(uint2*)&bt[px*104 + ch0 + j2*4] = w2;
    }
    sA[grp*128 + px] = s;
    sB[grp*128 + px] = ss;
  }
  __syncthreads();
  if (tid < 128){
    float s = sA[tid] + sA[128+tid] + sA[256+tid] + sA[384+tid];
    float ss = sB[tid] + sB[128+tid] + sB[256+tid] + sB[384+tid];
    float mu = s*(1.f/CC);
    float var = ss*(1.f/CC) - mu*mu;
    sm[tid] = mu;
    sr[tid] = rsqrtf(var + 1e-5f);
  }
  __syncthreads();
  int row = wid*16 + lr;
  float rs = sr[row];
  float nmr = -sm[row]*rs;

  int hrow = row*104;
  f32x4 acc2[6];
  #pragma unroll
  for (int mf = 0; mf < 6; ++mf) acc2[mf] = (f32x4){0,0,0,0};

  for (int cc = 0; cc < 4; ++cc){
    f32x4 acc1[6];
    #pragma unroll
    for (int mf = 0; mf < 6; ++mf) acc1[mf] = (f32x4){0,0,0,0};
    #pragma unroll
    for (int ks = 0; ks < 3; ++ks){
      bf16x8 af[6];
      #pragma unroll
      for (int mf = 0; mf < 6; ++mf)
        af[mf] = *(const bf16x8*)(Wb1 + (size_t)((cc*18 + ks*6 + mf)*64 + lane)*8);
      bf16x8 bfr = *(const bf16x8*)&bt[hrow + ks*32 + lg*8];
      #pragma unroll
      for (int mf = 0; mf < 6; ++mf)
        acc1[mf] = __builtin_amdgcn_mfma_f32_16x16x32_bf16(af[mf], bfr, acc1[mf], 0, 0, 0);
    }
    #pragma unroll
    for (int mf = 0; mf < 6; ++mf){
      float4 sv = *(const float4*)&s11[cc*96 + mf*16 + lg*4];
      float4 cv = *(const float4*)&c1 [cc*96 + mf*16 + lg*4];
      float g0 = gelu_f(fmaf(rs, acc1[mf][0], fmaf(nmr, sv.x, cv.x)));
      float g1 = gelu_f(fmaf(rs, acc1[mf][1], fmaf(nmr, sv.y, cv.y)));
      float g2 = gelu_f(fmaf(rs, acc1[mf][2], fmaf(nmr, sv.z, cv.z)));
      float g3 = gelu_f(fmaf(rs, acc1[mf][3], fmaf(nmr, sv.w, cv.w)));
      uint2 pw;
      pw.x = pk_bf16(g0, g1);
      pw.y = pk_bf16(g2, g3);
      *(uint2*)&hs[hrow + mf*16 + lg*4] = pw;
    }
    #pragma unroll
    for (int ks = 0; ks < 3; ++ks){
      bf16x8 a2[6];
      #pragma unroll
      for (int mf2 = 0; mf2 < 6; ++mf2)
        a2[mf2] = *(const bf16x8*)(Wb2 + (size_t)(((cc*3 + ks)*6 + mf2)*64 + lane)*8);
      bf16x8 bfr2 = *(const bf16x8*)&hs[hrow + ks*32 + lg*8];
      #pragma unroll
      for (int mf2 = 0; mf2 < 6; ++mf2)
        acc2[mf2] = __builtin_amdgcn_mfma_f32_16x16x32_bf16(a2[mf2], bfr2, acc2[mf2], 0, 0, 0);
    }
  }
  #pragma unroll
  for (int mf = 0; mf < 6; ++mf){
    #pragma unroll
    for (int r = 0; r < 4; ++r){
      int mm = mf*16 + lg*4 + r;
      size_t idx = ((size_t)b*CC + mm)*LL + lb0 + row;
      float vv = acc2[mf][r] + c2[mm] + bf2f(X[idx]);
      X[idx] = f2bf(vv);
    }
  }
}

// ---------------- depthwise 3x3 + SiLU (bf16 in/out), fused transpose ----------------
__global__ __launch_bounds__(256) void k_dwconv_silu_t(const u16* __restrict__ u,
      u16* __restrict__ v, u16* __restrict__ vT, const float* __restrict__ cw){
  __shared__ float tl[32][33];
  int bc = blockIdx.z;
  int c = bc % CC;
  int w0 = blockIdx.x*32, h0 = blockIdx.y*32;
  const u16* up = u + (size_t)bc*LL;
  const float* k9 = cw + c*9;
  int t = threadIdx.x;
  int wl = (t & 7)*4, hl = t >> 3;
  int h = h0 + hl, w = w0 + wl;
  float acc[4] = {0.f,0.f,0.f,0.f};
  #pragma unroll
  for (int dh = -1; dh <= 1; ++dh){
    int h2 = h + dh;
    if (h2 < 0 || h2 >= HH) continue;
    const u16* row = up + (size_t)h2*WW + w;
    ushort4 mq = *(const ushort4*)row;
    float m0 = bf2f(mq.x), m1 = bf2f(mq.y), m2 = bf2f(mq.z), m3 = bf2f(mq.w);
    float lft = (w > 0) ? bf2f(row[-1]) : 0.f;
    float rgt = (w + 4 < WW) ? bf2f(row[4]) : 0.f;
    float k0 = k9[(dh+1)*3], k1 = k9[(dh+1)*3+1], k2 = k9[(dh+1)*3+2];
    acc[0] += lft*k0 + m0*k1 + m1*k2;
    acc[1] += m0*k0 + m1*k1 + m2*k2;
    acc[2] += m1*k0 + m2*k1 + m3*k2;
    acc[3] += m2*k0 + m3*k1 + rgt*k2;
  }
  float s[4];
  #pragma unroll
  for (int j = 0; j < 4; ++j){
    float a = acc[j];
    float e = __expf(-a);
    s[j] = a * __builtin_amdgcn_rcpf(1.f + e);
    tl[wl + j][hl] = s[j];
  }
  uint2 pw;
  pw.x = pk_bf16(s[0], s[1]);
  pw.y = pk_bf16(s[2], s[3]);
  *(uint2*)&v[(size_t)bc*LL + (size_t)h*WW + w] = pw;
  __syncthreads();
  int ww = t >> 3, hh4 = (t & 7)*4;
  uint2 po;
  po.x = pk_bf16(tl[ww][hh4],   tl[ww][hh4+1]);
  po.y = pk_bf16(tl[ww][hh4+2], tl[ww][hh4+3]);
  *(uint2*)&vT[(size_t)bc*LL + (size_t)(w0 + ww)*HH + h0 + hh4] = po;
}

// ---------------- x-projection (bf16 src, bf16 G out) ----------------
__global__ void k_xproj(const u16* __restrict__ v, const u16* __restrict__ vT,
                        u16* __restrict__ G, const float* __restrict__ xpw){
  int which = blockIdx.y;
  const u16* src = which ? vT : v;
  int kA = which ? 1 : 0, kB = which ? 3 : 2;
  size_t i = (size_t)blockIdx.x*256 + threadIdx.x;
  if (i >= (size_t)BT*LL) return;
  int b = (int)(i / LL), l = (int)(i % LL);
  const u16* sp = src + (size_t)b*CC*LL + l;
  const float* wA = xpw + (size_t)kA*8*CC;
  const float* wB = xpw + (size_t)kB*8*CC;
  float aA[8], aB[8];
  #pragma unroll
  for (int d = 0; d < 8; ++d){ aA[d] = 0.f; aB[d] = 0.f; }
  for (int c = 0; c < CC; ++c){
    float xv = bf2f(sp[(size_t)c*LL]);
    #pragma unroll
    for (int d = 0; d < 8; ++d){
      aA[d] = fmaf(wA[d*CC + c], xv, aA[d]);
      aB[d] = fmaf(wB[d*CC + c], xv, aB[d]);
    }
  }
  u16* gA = G + (((size_t)b*KD + kA)*8)*LL + l;
  u16* gB = G + (((size_t)b*KD + kB)*8)*LL + l;
  #pragma unroll
  for (int d = 0; d < 8; ++d){ gA[(size_t)d*LL] = f2bf(aA[d]); gB[(size_t)d*LL] = f2bf(aB[d]); }
}

// ---------------- scan v7: single-chain, 8 waves/block, 2048/wave, 8 elems/lane ----------------
__device__ __forceinline__ void ldbf8(const u16* p, float* o){
  uint4 t = *(const uint4*)p;
  o[0]=bf2f((u16)(t.x & 0xffff)); o[1]=bf2f((u16)(t.x >> 16));
  o[2]=bf2f((u16)(t.y & 0xffff)); o[3]=bf2f((u16)(t.y >> 16));
  o[4]=bf2f((u16)(t.z & 0xffff)); o[5]=bf2f((u16)(t.z >> 16));
  o[6]=bf2f((u16)(t.w & 0xffff)); o[7]=bf2f((u16)(t.w >> 16));
}
__device__ __forceinline__ void rev8(float* a){
  #pragma unroll
  for (int i = 0; i < 4; ++i){ float t0 = a[i]; a[i] = a[7-i]; a[7-i] = t0; }
}

__global__ __launch_bounds__(512) void k_scan3(const u16* __restrict__ G,
                       const u16* __restrict__ v, const u16* __restrict__ vT,
                       u16* __restrict__ Y,
                       const float* __restrict__ dtw_, const float* __restrict__ dtb_,
                       const float* __restrict__ Alog_, const float* __restrict__ Ds_){
  const size_t SZ = (size_t)BT*CC*LL;
  const float LOG2E = 1.4426950408889634f, LN2 = 0.6931471805599453f;
  int wid = threadIdx.x >> 6, lane = threadIdx.x & 63;
  int tile = wid;                              // 0..7 (8 tiles x 2048 = 16384)
  int sy = blockIdx.y;
  bool rev = (blockIdx.z != 0);
  int c = sy % CC; int t2 = sy / CC; int kk = t2 & 1; int b = t2 >> 1;
  int k = (rev ? 2 : 0) + kk;
  const u16* src = (kk ? vT : v) + ((size_t)b*CC + c)*LL;
  const u16* g = G + (((size_t)b*KD + k)*8)*LL;
  float dtw[RR];
  #pragma unroll
  for (int r = 0; r < RR; ++r) dtw[r] = dtw_[((size_t)k*CC + c)*RR + r];
  float dtb = dtb_[k*CC + c];
  float A  = -__expf(Alog_[k*CC + c]);
  float Dv = Ds_[k*CC + c];
  u16* yout = Y + (size_t)k*SZ + ((size_t)b*CC + c)*LL;

  int lstore0 = tile*STPW;
  float carry = 0.f;
  for (int p = 0; p < 1 + STPW/WARM; ++p){
    int base = lstore0 - WARM + p*WARM;
    if (base < 0) continue;                    // tile 0: no warm-up
    bool st = (base >= lstore0);
    int l = base + (lane<<3);
    int ga = rev ? (LL-8-l) : l;
    float dsum[8], g6b[8], g7b[8], xb[8];
    #pragma unroll
    for (int i = 0; i < 8; ++i) dsum[i] = dtb;
    #pragma unroll
    for (int r = 0; r < RR; ++r){
      float t8[8];
      ldbf8(g + (size_t)r*LL + ga, t8);
      #pragma unroll
      for (int i = 0; i < 8; ++i) dsum[i] = fmaf(t8[i], dtw[r], dsum[i]);
    }
    ldbf8(g + (size_t)6*LL + ga, g6b);
    if (st){
      ldbf8(g + (size_t)7*LL + ga, g7b);
    } else {
      #pragma unroll
      for (int i = 0; i < 8; ++i) g7b[i] = 0.f;
    }
    ldbf8(src + ga, xb);
    if (rev){ rev8(dsum); rev8(g6b); rev8(g7b); rev8(xb); }
    float av[8], bt[8];
    #pragma unroll
    for (int i = 0; i < 8; ++i){
      float dl2 = dsum[i]*LOG2E;
      float y = flog2(1.f + fexp2(dl2));
      y = (dsum[i] > 20.f) ? dl2 : y;
      float delta = y*LN2;
      av[i] = fexp2(A*y);
      bt[i] = delta * g6b[i] * xb[i];
    }
    float P = av[0], Q = bt[0];
    #pragma unroll
    for (int i = 1; i < 8; ++i){ Q = fmaf(av[i], Q, bt[i]); P *= av[i]; }
    #pragma unroll
    for (int off = 1; off < 64; off <<= 1){
      float Pp = __shfl_up(P, (unsigned)off);
      float Qp = __shfl_up(Q, (unsigned)off);
      if (lane >= off){ Q = fmaf(P, Qp, Q); P *= Pp; }
    }
    float Pe = __shfl_up(P, 1u), Qe = __shfl_up(Q, 1u);
    if (lane == 0){ Pe = 1.f; Qe = 0.f; }
    float h = fmaf(Pe, carry, Qe);
    if (st){
      float ys[8];
      #pragma unroll
      for (int i = 0; i < 8; ++i){
        h = fmaf(av[i], h, bt[i]);
        ys[i] = fmaf(g7b[i], h, Dv*xb[i]);
      }
      carry = __shfl(h, 63);
      if (rev) rev8(ys);
      uint4 pw;
      pw.x = pk_bf16(ys[0], ys[1]);
      pw.y = pk_bf16(ys[2], ys[3]);
      pw.z = pk_bf16(ys[4], ys[5]);
      pw.w = pk_bf16(ys[6], ys[7]);
      *(uint4*)&yout[ga] = pw;
    } else {
      #pragma unroll
      for (int i = 0; i < 8; ++i) h = fmaf(av[i], h, bt[i]);
      carry = __shfl(h, 63);
    }
  }
}

// ---------------- combine (bf16 in/out): z = (y0+y2) + transpose(y1+y3) ----------------
__global__ __launch_bounds__(256) void k_combine4(const u16* __restrict__ Y, u16* __restrict__ z){
  const size_t SZ = (size_t)BT*CC*LL;
  __shared__ float tl[64][65];
  int bc = blockIdx.z;
  int w0 = blockIdx.x*64;
  int t = threadIdx.x;
  const u16* y1p = Y + SZ   + (size_t)bc*LL;
  const u16* y3p = Y + 3*SZ + (size_t)bc*LL;
  {
    int wl = t >> 2;            // 0..63
    int h0 = (t & 3)*16;        // 0,16,32,48
    size_t base = (size_t)(w0 + wl)*HH + h0;
    #pragma unroll
    for (int j = 0; j < 4; ++j){
      ushort4 a = *(const ushort4*)&y1p[base + j*4];
      ushort4 bq = *(const ushort4*)&y3p[base + j*4];
      tl[wl][h0 + j*4 + 0] = bf2f(a.x) + bf2f(bq.x);
      tl[wl][h0 + j*4 + 1] = bf2f(a.y) + bf2f(bq.y);
      tl[wl][h0 + j*4 + 2] = bf2f(a.z) + bf2f(bq.z);
      tl[wl][h0 + j*4 + 3] = bf2f(a.w) + bf2f(bq.w);
    }
  }
  __syncthreads();
  const u16* y0p = Y +        (size_t)bc*LL;
  const u16* y2p = Y + 2*SZ + (size_t)bc*LL;
  u16* zp = z + (size_t)bc*LL;
  {
    int h = t >> 2;             // 0..63
    int wq = (t & 3)*16;        // 0,16,32,48
    #pragma unroll
    for (int j = 0; j < 4; ++j){
      int wl = wq + j*4;
      size_t idx = (size_t)h*WW + w0 + wl;
      ushort4 a = *(const ushort4*)&y0p[idx];
      ushort4 bq = *(const ushort4*)&y2p[idx];
      ushort4 o;
      o.x = f2bf(bf2f(a.x) + bf2f(bq.x) + tl[wl+0][h]);
      o.y = f2bf(bf2f(a.y) + bf2f(bq.y) + tl[wl+1][h]);
      o.z = f2bf(bf2f(a.z) + bf2f(bq.z) + tl[wl+2][h]);
      o.w = f2bf(bf2f(a.w) + bf2f(bq.w) + tl[wl+3][h]);
      *(ushort4*)&zp[idx] = o;
    }
  }
}

// ---------------- final output split/average (bf16 X -> f32 out) ----------------
__global__ void k_output(const u16* __restrict__ X, float* __restrict__ out){
  size_t i = (size_t)blockIdx.x*256 + threadIdx.x;
  size_t half = (size_t)2*CC*HH*128;
  if (i >= half) return;
  int w = i % 128; size_t r = i / 128;
  int h = r % HH; size_t bc = r / HH;
  size_t fwd = (bc*HH + h)*WW;
  size_t bwd = ((bc + (size_t)2*CC)*HH + h)*WW;
  out[i]        = 0.5f*(bf2f(X[fwd + w])       + bf2f(X[bwd + (WW-1-w)]));
  out[half + i] = 0.5f*(bf2f(X[fwd + 128 + w]) + bf2f(X[bwd + (127 - w)]));
}

extern "C" void kernel_launch(void* const* d_in, const int* in_sizes, int n_in,
                              void* d_out, int out_size, void* d_ws, size_t ws_size,
                              hipStream_t stream){
  const float* x0        = (const float*)d_in[0];
  const float* x1        = (const float*)d_in[1];
  const float* norm_w    = (const float*)d_in[2];
  const float* norm_b    = (const float*)d_in[3];
  const float* in_proj_w = (const float*)d_in[4];
  const float* conv_w    = (const float*)d_in[5];
  const float* x_proj_w  = (const float*)d_in[6];
  const float* dt_w      = (const float*)d_in[7];
  const float* dt_b      = (const float*)d_in[8];
  const float* A_logs    = (const float*)d_in[9];
  const float* Ds        = (const float*)d_in[10];
  const float* out_norm_w= (const float*)d_in[11];
  const float* out_norm_b= (const float*)d_in[12];
  const float* out_proj_w= (const float*)d_in[13];
  const float* norm2_w   = (const float*)d_in[14];
  const float* norm2_b   = (const float*)d_in[15];
  const float* fc1_w     = (const float*)d_in[16];
  const float* fc1_b     = (const float*)d_in[17];
  const float* fc2_w     = (const float*)d_in[18];
  const float* fc2_b     = (const float*)d_in[19];

  const size_t SZ = (size_t)BT*CC*LL;            // 6,291,456 elems
  u16* Xb  = (u16*)d_ws;
  u16* tB  = Xb + SZ;
  u16* uB  = tB + SZ;
  u16* vB  = uB + SZ;
  u16* vTB = vB + SZ;
  u16* Gb  = vTB + SZ;                           // BT*KD*8*LL u16
  u16* Yb  = Gb + (size_t)BT*KD*8*LL;            // 4*SZ u16
  float* wsl = (float*)(Yb + 4*SZ);              // weight slots

  float* p0 = wsl;
  u16*  WbI0 = (u16*)p0;          float* s1I0 = p0 + 4608;  float* cI0 = p0 + 4704;
  u16*  WbO0 = (u16*)(p0+4800);   float* s1O0 = p0 + 9408;  float* cO0 = p0 + 9504;
  u16*  Wb10 = (u16*)(p0+9600);   float* s110 = p0 + 28032; float* c10 = p0 + 28416;
  u16*  Wb20 = (u16*)(p0+28800);  float* s120 = p0 + 47232; float* c20 = p0 + 47328;

  k_prepw<96,96,false,true,false><<<dim3(2,NLAY),64,0,stream>>>(in_proj_w, norm_w, norm_b, nullptr, WbI0, s1I0, cI0);
  k_prepw<96,96,false,true,false><<<dim3(2,NLAY),64,0,stream>>>(out_proj_w, out_norm_w, out_norm_b, nullptr, WbO0, s1O0, cO0);
  k_prepw<384,96,true,true,true><<<dim3(6,NLAY),64,0,stream>>>(fc1_w, norm2_w, norm2_b, fc1_b, Wb10, s110, c10);
  k_prepw<96,384,false,false,true><<<dim3(2,NLAY),64,0,stream>>>(fc2_w, nullptr, nullptr, fc2_b, Wb20, s120, c20);

  k_build<<<(2*CC*HH*WW + 255)/256, 256, 0, stream>>>(x0, x1, Xb);

  for (int lay = 0; lay < NLAY; ++lay){
    size_t so = (size_t)lay*SLOTF;
    const u16* WbI = WbI0 + so*2; const float* s1I = s1I0 + so; const float* cI = cI0 + so;
    const u16* WbO = WbO0 + so*2; const float* s1O = s1O0 + so; const float* cO = cO0 + so;
    const u16* Wb1 = Wb10 + so*2; const float* s11 = s110 + so; const float* c1 = c10 + so;
    const u16* Wb2 = Wb20 + so*2; const float* c2 = c20 + so;
    const float* cw  = conv_w    + (size_t)lay*CC*9;
    const float* xpw = x_proj_w  + (size_t)lay*KD*8*CC;
    const float* dw  = dt_w      + (size_t)lay*KD*CC*RR;
    const float* db  = dt_b      + (size_t)lay*KD*CC;
    const float* Al  = A_logs    + (size_t)lay*KD*CC;
    const float* Dp  = Ds        + (size_t)lay*KD*CC;

    k_proj<false><<<dim3(BT*LL/128),256,0,stream>>>(WbI, Xb, uB, nullptr, s1I, cI);
    k_dwconv_silu_t<<<dim3(8,2,BT*CC), 256, 0, stream>>>(uB, vB, vTB, cw);
    k_xproj<<<dim3(BT*LL/256, 2), 256, 0, stream>>>(vB, vTB, Gb, xpw);
    k_scan3<<<dim3(1,768,2), 512, 0, stream>>>(Gb, vB, vTB, Yb, dw, db, Al, Dp);
    k_combine4<<<dim3(4,1,BT*CC), 256, 0, stream>>>(Yb, tB);
    k_proj<true><<<dim3(BT*LL/128),256,0,stream>>>(WbO, tB, Xb, Xb, s1O, cO);
    k_mlp<<<dim3(BT*LL/128),512,0,stream>>>(Wb1, Wb2, Xb, s11, c1, c2);
  }

  k_output<<<(unsigned)(((size_t)2*CC*HH*128 + 255)/256), 256, 0, stream>>>(Xb, (float*)d_out);
}